// Round 9
// baseline (305.323 us; speedup 1.0000x reference)
//
#include <hip/hip_runtime.h>
#include <hip/hip_bf16.h>

// ---------- types ----------
typedef float f32x4 __attribute__((ext_vector_type(4)));
typedef __bf16 bf16x8 __attribute__((ext_vector_type(8)));
typedef _Float16 f16x2 __attribute__((ext_vector_type(2)));
typedef _Float16 f16x4 __attribute__((ext_vector_type(4)));

// fp32 -> bf16 RNE
__device__ __forceinline__ unsigned short f2bf(float f){
  unsigned int u = __builtin_bit_cast(unsigned int, f);
  u += 0x7fffu + ((u >> 16) & 1u);
  return (unsigned short)(u >> 16);
}
__device__ __forceinline__ float bf2f(unsigned short h){
  return __builtin_bit_cast(float, (unsigned int)h << 16);
}

// packed f32x2 -> f16x2 (v_cvt_pkrtz_f16_f32), with type-identity fix
__device__ __forceinline__ f16x2 pkrtz(float a, float b){
  return __builtin_bit_cast(f16x2, __builtin_amdgcn_cvt_pkrtz(a, b));
}

__device__ __forceinline__ void glds16(const void* g, void* l){
  __builtin_amdgcn_global_load_lds((const __attribute__((address_space(1))) void*)g,
                                   (__attribute__((address_space(3))) void*)l, 16, 0, 0);
}

__device__ __forceinline__ f32x4 mfma16(bf16x8 a, bf16x8 b, f32x4 c){
  return __builtin_amdgcn_mfma_f32_16x16x32_bf16(a, b, c, 0, 0, 0);
}
__device__ __forceinline__ f32x4 mfma16h(f16x4 a, f16x4 b, f32x4 c){
  return __builtin_amdgcn_mfma_f32_16x16x16f16(a, b, c, 0, 0, 0);
}

#if __has_builtin(__builtin_amdgcn_exp2f)
__device__ __forceinline__ float exp2v(float x){ return __builtin_amdgcn_exp2f(x); }
#else
__device__ __forceinline__ float exp2v(float x){ return exp2f(x); }
#endif

// ---------- kernel: detect mask dtype (bool-bytes vs int32) ----------
__global__ void detect_kernel(const unsigned int* __restrict__ m, int* __restrict__ flag){
  int t = threadIdx.x;
  int bad = 0;
  for(int i = t; i < 4096; i += 256) bad |= (m[i] > 1u);
  unsigned long long b = __ballot(bad != 0);
  __shared__ int sbuf[4];
  if((t & 63) == 0) sbuf[t >> 6] = (b != 0ull);
  __syncthreads();
  if(t == 0) flag[0] = (sbuf[0] | sbuf[1] | sbuf[2] | sbuf[3]) ? 0 : 1; // 1 => int32
}

// ---------- kernel: pack mask into bits (mp[row][64 words]) ----------
__global__ void pack_mask_kernel(const unsigned char* __restrict__ m8,
                                 unsigned int* __restrict__ mp,
                                 const int* __restrict__ flag){
  const int wid = threadIdx.x >> 6, lane = threadIdx.x & 63;
  const int row = blockIdx.x * 4 + wid;            // 0..4095 (b*2048+q)
  const int is32 = flag[0];
  const int* m32 = (const int*)m8;
  for(int c0 = 0; c0 < 2048; c0 += 64){
    int mv = is32 ? m32[(size_t)row*2048 + c0 + lane]
                  : (int)m8[(size_t)row*2048 + c0 + lane];
    unsigned long long b = __ballot(mv != 0);
    if(lane == 0){
      mp[(size_t)row*64 + (c0 >> 5)]     = (unsigned int)b;
      mp[(size_t)row*64 + (c0 >> 5) + 1] = (unsigned int)(b >> 32);
    }
  }
}

// ---------- kernel: fp32 -> bf16 convert, all three of q/k/v ----------
__global__ void cvt3_kernel(const float* __restrict__ qs, const float* __restrict__ ks,
                            const float* __restrict__ vs, unsigned short* __restrict__ dst){
  const float* src = (blockIdx.y==0)?qs:(blockIdx.y==1)?ks:vs;
  unsigned short* d = dst + (size_t)blockIdx.y * 4194304;
  int i = blockIdx.x * 256 + threadIdx.x;
  const float4* s = (const float4*)src;
  float4 a = s[2*i], b = s[2*i+1];
  union { unsigned short h[8]; uint4 v; } o;
  o.h[0]=f2bf(a.x); o.h[1]=f2bf(a.y); o.h[2]=f2bf(a.z); o.h[3]=f2bf(a.w);
  o.h[4]=f2bf(b.x); o.h[5]=f2bf(b.y); o.h[6]=f2bf(b.z); o.h[7]=f2bf(b.w);
  ((uint4*)d)[i] = o.v;
}

// ---------- kernel: W[1024][1024] f32 -> W^T bf16 (Wq scaled by 0.125*log2e) ----------
__global__ void transW_kernel(const float* __restrict__ Wq, const float* __restrict__ Wk,
                              const float* __restrict__ Wv, const float* __restrict__ Wo,
                              unsigned short* __restrict__ WT){
  const float* W = (blockIdx.y==0)?Wq:(blockIdx.y==1)?Wk:(blockIdx.y==2)?Wv:Wo;
  const float scale = (blockIdx.y==0) ? 0.1803368801111601f : 1.0f;
  unsigned short* D = WT + (size_t)blockIdx.y * 1048576;
  int r0 = (blockIdx.x >> 4) * 64, c0 = (blockIdx.x & 15) * 64;
  __shared__ unsigned short T[64][65];
  int t = threadIdx.x;
  {
    int r = t >> 2, cb = (t & 3) * 16;
    const float4* src = (const float4*)(W + (size_t)(r0 + r) * 1024 + (c0 + cb));
    float4 v0 = src[0], v1 = src[1], v2 = src[2], v3 = src[3];
    float vals[16] = {v0.x,v0.y,v0.z,v0.w, v1.x,v1.y,v1.z,v1.w,
                      v2.x,v2.y,v2.z,v2.w, v3.x,v3.y,v3.z,v3.w};
    #pragma unroll
    for(int j=0;j<16;j++) T[cb + j][r] = f2bf(vals[j] * scale);
  }
  __syncthreads();
  {
    int c = t >> 2, rb = (t & 3) * 16;
    union { unsigned short h[16]; uint4 v[2]; } o;
    #pragma unroll
    for(int j=0;j<16;j++) o.h[j] = T[c][rb + j];
    uint4* dp = (uint4*)(D + (size_t)(c0 + c) * 1024 + (r0 + rb));
    dp[0] = o.v[0]; dp[1] = o.v[1];
  }
}

// ---------- kernel: C[M=4096][N=1024] = A @ BT^T, bf16, 128x128 tile, BK=64 ----------
// OUTF32=1: f32 store to Cf.  OUTF32=0: bf16 store; blockIdx.z==2 writes per-head
// transposed V as F16 directly: Vt[(b*16+h)*64+d][s].
template<int OUTF32>
__global__ __launch_bounds__(256,2) void gemm_bt(
    const unsigned short* __restrict__ A0, const unsigned short* __restrict__ A1, const unsigned short* __restrict__ A2,
    const unsigned short* __restrict__ B0, const unsigned short* __restrict__ B1, const unsigned short* __restrict__ B2,
    unsigned short* __restrict__ C0, unsigned short* __restrict__ C1, unsigned short* __restrict__ C2,
    float* __restrict__ Cf)
{
  const unsigned short* A  = (blockIdx.z==0)?A0:(blockIdx.z==1)?A1:A2;
  const unsigned short* BT = (blockIdx.z==0)?B0:(blockIdx.z==1)?B1:B2;
  unsigned short* C        = (blockIdx.z==0)?C0:(blockIdx.z==1)?C1:C2;
  __shared__ unsigned short Asm[128*64];
  __shared__ unsigned short Bsm[128*64];
  const int wid = threadIdx.x >> 6, lane = threadIdx.x & 63;
  const int m0 = blockIdx.x * 128, n0 = blockIdx.y * 128;
  const int wrow = wid >> 1, wcol = wid & 1;
  const int li = lane & 15, lg = lane >> 4, li7 = lane & 7;
  f32x4 acc[4][4] = {};
  const int sr = lane >> 3;       // 0..7 (row within 8-row chunk)
  const int sc = lane & 7;        // 0..7 (16B block within 128B row)

  for(int kt = 0; kt < 16; ++kt){
    const int kofs = kt * 64;
    #pragma unroll
    for(int i=0;i<4;i++){
      int r = wid*32 + i*8 + sr;             // tile-local row; r&7 == sr
      int blk = sc ^ sr;                     // source-side swizzle
      glds16(A  + (size_t)(m0 + r)*1024 + kofs + blk*8, &Asm[(wid*32 + i*8)*64]);
      glds16(BT + (size_t)(n0 + r)*1024 + kofs + blk*8, &Bsm[(wid*32 + i*8)*64]);
    }
    __syncthreads();
    #pragma unroll
    for(int kk=0; kk<2; kk++){
      bf16x8 af[4], bfv[4];
      #pragma unroll
      for(int fm=0; fm<4; fm++){
        int row = wrow*64 + fm*16 + li;      // row&7 == li7
        int blk = (kk*4 + lg) ^ li7;
        af[fm] = *(const bf16x8*)&Asm[row*64 + blk*8];
      }
      #pragma unroll
      for(int fn=0; fn<4; fn++){
        int row = wcol*64 + fn*16 + li;
        int blk = (kk*4 + lg) ^ li7;
        bfv[fn] = *(const bf16x8*)&Bsm[row*64 + blk*8];
      }
      __builtin_amdgcn_s_setprio(1);
      #pragma unroll
      for(int fm=0; fm<4; fm++)
        #pragma unroll
        for(int fn=0; fn<4; fn++)
          acc[fm][fn] = mfma16(af[fm], bfv[fn], acc[fm][fn]);
      __builtin_amdgcn_s_setprio(0);
    }
    __syncthreads();
  }
  if(OUTF32 == 0 && blockIdx.z == 2){
    // V: write transposed per head in F16.  4 consecutive s-rows pack to one 8B store.
    #pragma unroll
    for(int fm=0; fm<4; fm++){
      #pragma unroll
      for(int fn=0; fn<4; fn++){
        int col  = n0 + wcol*64 + fn*16 + li;        // h*64 + d
        int rowb = m0 + wrow*64 + fm*16 + lg*4;      // b*2048 + s
        int bq = rowb >> 11, s = rowb & 2047;
        union { f16x2 h2[2]; unsigned long long u; } o;
        o.h2[0] = pkrtz(acc[fm][fn][0], acc[fm][fn][1]);
        o.h2[1] = pkrtz(acc[fm][fn][2], acc[fm][fn][3]);
        *(unsigned long long*)&C[((size_t)(bq*16 + (col>>6))*64 + (col&63))*2048 + s] = o.u;
      }
    }
  } else {
    #pragma unroll
    for(int fm=0; fm<4; fm++){
      #pragma unroll
      for(int fn=0; fn<4; fn++){
        int col  = n0 + wcol*64 + fn*16 + li;
        int rowb = m0 + wrow*64 + fm*16 + lg*4;
        #pragma unroll
        for(int r=0;r<4;r++){
          if(OUTF32) Cf[(size_t)(rowb + r)*1024 + col] = acc[fm][fn][r];
          else       C [(size_t)(rowb + r)*1024 + col] = f2bf(acc[fm][fn][r]);
        }
      }
    }
  }
}

// ---------- kernel: flash attention v8 (KV-split-2) ----------
// v7 structure (16x16 swapped-QK, fixed-exponent softmax, 2 q-groups/wave,
// lane-local f16 PV) split across 2 blocks per (qtile,bh), one per KV half.
// Each block writes unnormalized partial O (f16) + partial row-sum l (f32).
// grid 1024 (swizzled) -> 4 blocks/CU, 16 waves/CU.
__global__ __launch_bounds__(256,4) void attn_kernel(
    const unsigned short* __restrict__ Q, const unsigned short* __restrict__ K,
    const unsigned short* __restrict__ Vt, _Float16* __restrict__ Of,
    float* __restrict__ Lp, const unsigned int* __restrict__ mp)
{
  __shared__ unsigned short Ksm[2][64*64];
  __shared__ unsigned short Vsm[2][64*64];     // f16 contents
  const int wid = threadIdx.x >> 6, lane = threadIdx.x & 63;
  const int orig = blockIdx.x;
  const int wg = (orig & 7) * 128 + (orig >> 3);   // XCD swizzle (1024 % 8 == 0)
  const int kvh = wg & 1, qt = (wg >> 1) & 15, bh = wg >> 5;
  const int b = bh >> 4, h = bh & 15;
  const int q0 = qt * 128;
  const int kbase = kvh * 1024;                    // this block's KV range start
  const int li = lane & 15, lg = lane >> 4;
  const int li7 = li & 7;

  const int rowA = b*2048 + q0 + wid*32 + li;      // lane's q-row, group A
  const int rowB = rowA + 16;                      // group B

  // Q fragments for both q-groups (Wq carries 0.125*log2e -> log2 domain)
  bf16x8 qfA[2], qfB[2];
  {
    const unsigned short* qa = Q + (size_t)rowA*1024 + h*64 + lg*8;
    const unsigned short* qb = Q + (size_t)rowB*1024 + h*64 + lg*8;
    qfA[0] = *(const bf16x8*)qa; qfA[1] = *(const bf16x8*)(qa + 32);
    qfB[0] = *(const bf16x8*)qb; qfB[1] = *(const bf16x8*)(qb + 32);
  }

  f32x4 oaccA[4] = {}, oaccB[4] = {};
  float lrowA = 0.f, lrowB = 0.f;

  const int srow = lane >> 3;
  const int sblk = (lane & 7) ^ srow;    // source-side swizzle for K/V staging

  // stage first tile of this half
  #pragma unroll
  for(int i=0;i<2;i++){
    int r = wid*16 + i*8 + srow;
    glds16(K  + (size_t)(b*2048 + kbase + r)*1024 + h*64 + sblk*8, &Ksm[0][(wid*16 + i*8)*64]);
    glds16(Vt + (size_t)(bh*64 + r)*2048 + kbase + sblk*8,         &Vsm[0][(wid*16 + i*8)*64]);
  }
  uint2 mwA = *(const uint2*)&mp[(size_t)rowA*64 + kvh*32];
  uint2 mwB = *(const uint2*)&mp[(size_t)rowB*64 + kvh*32];
  uint2 mwAn, mwBn;
  __syncthreads();

  int buf = 0;
  for(int tt = 0; tt < 16; ++tt){
    const int kv0 = kbase + tt * 64;
    if(tt < 15){
      #pragma unroll
      for(int i=0;i<2;i++){
        int r = wid*16 + i*8 + srow;
        glds16(K  + (size_t)(b*2048 + kv0 + 64 + r)*1024 + h*64 + sblk*8, &Ksm[buf^1][(wid*16 + i*8)*64]);
        glds16(Vt + (size_t)(bh*64 + r)*2048 + kv0 + 64 + sblk*8,         &Vsm[buf^1][(wid*16 + i*8)*64]);
      }
      mwAn = *(const uint2*)&mp[(size_t)rowA*64 + (size_t)((kv0 + 64) >> 5)];
      mwBn = *(const uint2*)&mp[(size_t)rowB*64 + (size_t)((kv0 + 64) >> 5)];
    }
    // S^T tiles for both q-groups: pX[f][j] = S[q][k=f*16+lg*4+j] (log2 domain)
    f32x4 pA[4], pB[4];
    __builtin_amdgcn_s_setprio(1);
    #pragma unroll
    for(int f=0; f<4; f++){
      f32x4 sa = {0.f,0.f,0.f,0.f}, sb = {0.f,0.f,0.f,0.f};
      #pragma unroll
      for(int kf=0; kf<2; kf++){
        int blk = (kf*4 + lg) ^ li7;
        bf16x8 kfr = *(const bf16x8*)&Ksm[buf][(f*16 + li)*64 + blk*8];
        sa = mfma16(kfr, qfA[kf], sa);
        sb = mfma16(kfr, qfB[kf], sb);
      }
      pA[f] = sa; pB[f] = sb;
    }
    __builtin_amdgcn_s_setprio(0);
    // fused softmax + PV, per k-16 subtile f: P stays lane-local (A-frag of 16x16x16)
    #pragma unroll
    for(int f=0; f<4; f++){
      unsigned int wA = (f < 2) ? mwA.x : mwA.y;
      unsigned int wB = (f < 2) ? mwB.x : mwB.y;
      float eA[4], eB[4];
      #pragma unroll
      for(int j=0;j<4;j++){
        unsigned int bitA = (wA >> ((f & 1)*16 + lg*4 + j)) & 1u;
        unsigned int bitB = (wB >> ((f & 1)*16 + lg*4 + j)) & 1u;
        float vA = exp2v(pA[f][j]);
        float vB = exp2v(pB[f][j]);
        eA[j] = bitA ? 0.f : vA;
        eB[j] = bitB ? 0.f : vB;
      }
      lrowA += (eA[0] + eA[1]) + (eA[2] + eA[3]);
      lrowB += (eB[0] + eB[1]) + (eB[2] + eB[3]);
      union { f16x2 h2[2]; f16x4 v; } ua, ub;
      ua.h2[0] = pkrtz(eA[0], eA[1]);
      ua.h2[1] = pkrtz(eA[2], eA[3]);
      ub.h2[0] = pkrtz(eB[0], eB[1]);
      ub.h2[1] = pkrtz(eB[2], eB[3]);
      const int blk = (f*2 + (lg >> 1)) ^ li7;
      const int sub = (lg & 1)*4;
      __builtin_amdgcn_s_setprio(1);
      #pragma unroll
      for(int dt=0; dt<4; dt++){
        f16x4 vf = *(const f16x4*)&Vsm[buf][(dt*16 + li)*64 + blk*8 + sub];
        oaccA[dt] = mfma16h(ua.v, vf, oaccA[dt]);
        oaccB[dt] = mfma16h(ub.v, vf, oaccB[dt]);
      }
      __builtin_amdgcn_s_setprio(0);
    }
    __syncthreads();
    mwA = mwAn; mwB = mwBn;
    buf ^= 1;
  }
  // reduce lane-partial sums; write partial O (f16, unnormalized) and partial l
  float rsA = lrowA, rsB = lrowB;
  rsA += __shfl_xor(rsA, 16); rsA += __shfl_xor(rsA, 32);
  rsB += __shfl_xor(rsB, 16); rsB += __shfl_xor(rsB, 32);
  #pragma unroll
  for(int r=0;r<4;r++){
    size_t rbA = (size_t)(b*2048 + q0 + wid*32 + lg*4 + r);
    size_t rbB = rbA + 16;
    #pragma unroll
    for(int dt=0; dt<4; dt++){
      Of[((size_t)kvh*4096 + rbA)*1024 + h*64 + 16*dt + li] = (_Float16)oaccA[dt][r];
      Of[((size_t)kvh*4096 + rbB)*1024 + h*64 + 16*dt + li] = (_Float16)oaccB[dt][r];
    }
  }
  if(lane < 16){
    int rA = b*2048 + q0 + wid*32 + lane;
    Lp[((size_t)kvh*4096 + rA)*16 + h]      = rsA;
    Lp[((size_t)kvh*4096 + rA + 16)*16 + h] = rsB;
  }
}

// ---------- kernel: combine the 2 KV-half partials -> bf16 Ob ----------
// grid 4096 (one row each), 256 thr (4 cols each).
__global__ void combine_kernel(const _Float16* __restrict__ Of,
                               const float* __restrict__ Lp,
                               unsigned short* __restrict__ Ob)
{
  const int row = blockIdx.x;
  const int col = threadIdx.x * 4;
  const int h = col >> 6;
  float l = Lp[(size_t)row*16 + h] + Lp[(size_t)(4096 + row)*16 + h];
  float inv = 1.0f / l;
  f16x4 o1 = *(const f16x4*)&Of[(size_t)row*1024 + col];
  f16x4 o2 = *(const f16x4*)&Of[(size_t)(4096 + row)*1024 + col];
  union { unsigned short h4[4]; unsigned long long u; } o;
  #pragma unroll
  for(int i=0;i<4;i++) o.h4[i] = f2bf(((float)o1[i] + (float)o2[i]) * inv);
  *(unsigned long long*)&Ob[(size_t)row*1024 + col] = o.u;
}

// ---------- launch ----------
extern "C" void kernel_launch(void* const* d_in, const int* in_sizes, int n_in,
                              void* d_out, int out_size, void* d_ws, size_t ws_size,
                              hipStream_t stream)
{
  const float* q_in = (const float*)d_in[0];
  const float* k_in = (const float*)d_in[1];
  const float* v_in = (const float*)d_in[2];
  const unsigned char* mask = (const unsigned char*)d_in[3];
  const float* Wq = (const float*)d_in[4];
  const float* Wk = (const float*)d_in[5];
  const float* Wv = (const float*)d_in[6];
  const float* Wo = (const float*)d_in[7];

  char* ws = (char*)d_ws;
  const size_t MB = 1024*1024;
  int* flag          = (int*)ws;                              // 256 B
  unsigned short* XQ = (unsigned short*)(ws + 256);           // 8 MB (-> Ob after attn)
  unsigned short* XK = (unsigned short*)(ws + 256 + 8*MB);    // 8 MB staging (-> Of after proj)
  unsigned short* XV = (unsigned short*)(ws + 256 + 16*MB);   // 8 MB staging (-> Of after proj)
  unsigned short* WT = (unsigned short*)(ws + 256 + 24*MB);   // 8 MB (4 matrices)
  unsigned short* Qb = (unsigned short*)(ws + 256 + 32*MB);   // 8 MB
  unsigned short* Kb = (unsigned short*)(ws + 256 + 40*MB);   // 8 MB
  unsigned short* Vt = (unsigned short*)(ws + 256 + 48*MB);   // 8 MB (f16, transposed, from GEMM)
  unsigned short* Ob = XQ;                                    // attention output (bf16)
  _Float16* Of       = (_Float16*)XK;                         // 16 MB partial O (2 halves)
  unsigned int* mpk  = (unsigned int*)WT;                     // 1 MB packed mask (WT[0] dead after proj)
  float* Lp          = (float*)(ws + 256 + 25*MB);            // 512 KB partial l (inside dead WT[0])

  detect_kernel<<<1, 256, 0, stream>>>((const unsigned int*)mask, flag);
  cvt3_kernel<<<dim3(2048,3), 256, 0, stream>>>(q_in, k_in, v_in, XQ);
  transW_kernel<<<dim3(256,4), 256, 0, stream>>>(Wq, Wk, Wv, Wo, WT);
  gemm_bt<0><<<dim3(32,8,3), 256, 0, stream>>>(XQ, XK, XV,
                                               WT, WT + 1048576, WT + 2097152,
                                               Qb, Kb, Vt, nullptr);
  pack_mask_kernel<<<1024, 256, 0, stream>>>(mask, mpk, flag);
  attn_kernel<<<1024, 256, 0, stream>>>(Qb, Kb, Vt, Of, Lp, mpk);
  combine_kernel<<<4096, 256, 0, stream>>>(Of, Lp, Ob);
  gemm_bt<1><<<dim3(32,8,1), 256, 0, stream>>>(Ob, Ob, Ob,
                                               WT + 3*1048576, WT + 3*1048576, WT + 3*1048576,
                                               nullptr, nullptr, nullptr, (float*)d_out);
}

// Round 10
// 151.092 us; speedup vs baseline: 2.0208x; 2.0208x over previous
//
#include <hip/hip_runtime.h>
#include <hip/hip_bf16.h>

// ---------- types ----------
typedef float f32x4 __attribute__((ext_vector_type(4)));
typedef __bf16 bf16x8 __attribute__((ext_vector_type(8)));
typedef _Float16 f16x2 __attribute__((ext_vector_type(2)));
typedef _Float16 f16x4 __attribute__((ext_vector_type(4)));

// fp32 -> bf16 RNE
__device__ __forceinline__ unsigned short f2bf(float f){
  unsigned int u = __builtin_bit_cast(unsigned int, f);
  u += 0x7fffu + ((u >> 16) & 1u);
  return (unsigned short)(u >> 16);
}
__device__ __forceinline__ float bf2f(unsigned short h){
  return __builtin_bit_cast(float, (unsigned int)h << 16);
}

// packed f32x2 -> f16x2 (v_cvt_pkrtz_f16_f32), with type-identity fix
__device__ __forceinline__ f16x2 pkrtz(float a, float b){
  return __builtin_bit_cast(f16x2, __builtin_amdgcn_cvt_pkrtz(a, b));
}

__device__ __forceinline__ void glds16(const void* g, void* l){
  __builtin_amdgcn_global_load_lds((const __attribute__((address_space(1))) void*)g,
                                   (__attribute__((address_space(3))) void*)l, 16, 0, 0);
}

__device__ __forceinline__ f32x4 mfma16(bf16x8 a, bf16x8 b, f32x4 c){
  return __builtin_amdgcn_mfma_f32_16x16x32_bf16(a, b, c, 0, 0, 0);
}
__device__ __forceinline__ f32x4 mfma16h(f16x4 a, f16x4 b, f32x4 c){
  return __builtin_amdgcn_mfma_f32_16x16x16f16(a, b, c, 0, 0, 0);
}

#if __has_builtin(__builtin_amdgcn_exp2f)
__device__ __forceinline__ float exp2v(float x){ return __builtin_amdgcn_exp2f(x); }
#else
__device__ __forceinline__ float exp2v(float x){ return exp2f(x); }
#endif

// ---------- kernel: pack mask into bits, self-detecting dtype ----------
// Every wave scans the first 1024 uint32 words (4 KB, in-range for bool too):
// random bool bytes give words>1 with P = 1-(1/8)^1024 ~ 1, so all-words<=1 => int32.
__global__ void pack_mask_kernel(const unsigned char* __restrict__ m8,
                                 unsigned int* __restrict__ mp){
  const int wid = threadIdx.x >> 6, lane = threadIdx.x & 63;
  const int row = blockIdx.x * 4 + wid;            // 0..4095 (b*2048+q)
  const unsigned int* w32 = (const unsigned int*)m8;
  int bad = 0;
  #pragma unroll
  for(int c = 0; c < 1024; c += 64) bad |= (w32[c + lane] > 1u);
  const int is32 = !__any(bad);
  const int* m32 = (const int*)m8;
  for(int c0 = 0; c0 < 2048; c0 += 64){
    int mv = is32 ? m32[(size_t)row*2048 + c0 + lane]
                  : (int)m8[(size_t)row*2048 + c0 + lane];
    unsigned long long b = __ballot(mv != 0);
    if(lane == 0){
      mp[(size_t)row*64 + (c0 >> 5)]     = (unsigned int)b;
      mp[(size_t)row*64 + (c0 >> 5) + 1] = (unsigned int)(b >> 32);
    }
  }
}

// ---------- kernel: fp32 -> bf16 convert, all three of q/k/v ----------
__global__ void cvt3_kernel(const float* __restrict__ qs, const float* __restrict__ ks,
                            const float* __restrict__ vs, unsigned short* __restrict__ dst){
  const float* src = (blockIdx.y==0)?qs:(blockIdx.y==1)?ks:vs;
  unsigned short* d = dst + (size_t)blockIdx.y * 4194304;
  int i = blockIdx.x * 256 + threadIdx.x;
  const float4* s = (const float4*)src;
  float4 a = s[2*i], b = s[2*i+1];
  union { unsigned short h[8]; uint4 v; } o;
  o.h[0]=f2bf(a.x); o.h[1]=f2bf(a.y); o.h[2]=f2bf(a.z); o.h[3]=f2bf(a.w);
  o.h[4]=f2bf(b.x); o.h[5]=f2bf(b.y); o.h[6]=f2bf(b.z); o.h[7]=f2bf(b.w);
  ((uint4*)d)[i] = o.v;
}

// ---------- kernel: W[1024][1024] f32 -> W^T bf16 (Wq scaled by 0.125*log2e) ----------
__global__ void transW_kernel(const float* __restrict__ Wq, const float* __restrict__ Wk,
                              const float* __restrict__ Wv, const float* __restrict__ Wo,
                              unsigned short* __restrict__ WT){
  const float* W = (blockIdx.y==0)?Wq:(blockIdx.y==1)?Wk:(blockIdx.y==2)?Wv:Wo;
  const float scale = (blockIdx.y==0) ? 0.1803368801111601f : 1.0f;
  unsigned short* D = WT + (size_t)blockIdx.y * 1048576;
  int r0 = (blockIdx.x >> 4) * 64, c0 = (blockIdx.x & 15) * 64;
  __shared__ unsigned short T[64][65];
  int t = threadIdx.x;
  {
    int r = t >> 2, cb = (t & 3) * 16;
    const float4* src = (const float4*)(W + (size_t)(r0 + r) * 1024 + (c0 + cb));
    float4 v0 = src[0], v1 = src[1], v2 = src[2], v3 = src[3];
    float vals[16] = {v0.x,v0.y,v0.z,v0.w, v1.x,v1.y,v1.z,v1.w,
                      v2.x,v2.y,v2.z,v2.w, v3.x,v3.y,v3.z,v3.w};
    #pragma unroll
    for(int j=0;j<16;j++) T[cb + j][r] = f2bf(vals[j] * scale);
  }
  __syncthreads();
  {
    int c = t >> 2, rb = (t & 3) * 16;
    union { unsigned short h[16]; uint4 v[2]; } o;
    #pragma unroll
    for(int j=0;j<16;j++) o.h[j] = T[c][rb + j];
    uint4* dp = (uint4*)(D + (size_t)(c0 + c) * 1024 + (r0 + rb));
    dp[0] = o.v[0]; dp[1] = o.v[1];
  }
}

// ---------- kernel: C[M=4096][N=1024] = A @ BT^T, bf16, 128x128 tile, BK=64 ----------
// Double-buffered LDS: stage tile kt+1 BEFORE computing tile kt (one barrier/iter).
// OUTF32=1: f32 store to Cf.  OUTF32=0: bf16 store; blockIdx.z==2 writes per-head
// transposed V as F16 directly: Vt[(b*16+h)*64+d][s].
template<int OUTF32>
__global__ __launch_bounds__(256,2) void gemm_bt(
    const unsigned short* __restrict__ A0, const unsigned short* __restrict__ A1, const unsigned short* __restrict__ A2,
    const unsigned short* __restrict__ B0, const unsigned short* __restrict__ B1, const unsigned short* __restrict__ B2,
    unsigned short* __restrict__ C0, unsigned short* __restrict__ C1, unsigned short* __restrict__ C2,
    float* __restrict__ Cf)
{
  const unsigned short* A  = (blockIdx.z==0)?A0:(blockIdx.z==1)?A1:A2;
  const unsigned short* BT = (blockIdx.z==0)?B0:(blockIdx.z==1)?B1:B2;
  unsigned short* C        = (blockIdx.z==0)?C0:(blockIdx.z==1)?C1:C2;
  __shared__ unsigned short Asm[2][128*64];
  __shared__ unsigned short Bsm[2][128*64];
  const int wid = threadIdx.x >> 6, lane = threadIdx.x & 63;
  const int m0 = blockIdx.x * 128, n0 = blockIdx.y * 128;
  const int wrow = wid >> 1, wcol = wid & 1;
  const int li = lane & 15, lg = lane >> 4, li7 = lane & 7;
  f32x4 acc[4][4] = {};
  const int sr = lane >> 3;       // 0..7 (row within 8-row chunk)
  const int sc = lane & 7;        // 0..7 (16B block within 128B row)
  const int sblk = sc ^ sr;       // source-side swizzle

  // prologue: stage tile 0
  #pragma unroll
  for(int i=0;i<4;i++){
    int r = wid*32 + i*8 + sr;
    glds16(A  + (size_t)(m0 + r)*1024 + sblk*8, &Asm[0][(wid*32 + i*8)*64]);
    glds16(BT + (size_t)(n0 + r)*1024 + sblk*8, &Bsm[0][(wid*32 + i*8)*64]);
  }
  __syncthreads();

  int buf = 0;
  for(int kt = 0; kt < 16; ++kt){
    if(kt < 15){
      const int kofs = (kt + 1) * 64;
      #pragma unroll
      for(int i=0;i<4;i++){
        int r = wid*32 + i*8 + sr;
        glds16(A  + (size_t)(m0 + r)*1024 + kofs + sblk*8, &Asm[buf^1][(wid*32 + i*8)*64]);
        glds16(BT + (size_t)(n0 + r)*1024 + kofs + sblk*8, &Bsm[buf^1][(wid*32 + i*8)*64]);
      }
    }
    #pragma unroll
    for(int kk=0; kk<2; kk++){
      bf16x8 af[4], bfv[4];
      #pragma unroll
      for(int fm=0; fm<4; fm++){
        int row = wrow*64 + fm*16 + li;      // row&7 == li7
        int blk = (kk*4 + lg) ^ li7;
        af[fm] = *(const bf16x8*)&Asm[buf][row*64 + blk*8];
      }
      #pragma unroll
      for(int fn=0; fn<4; fn++){
        int row = wcol*64 + fn*16 + li;
        int blk = (kk*4 + lg) ^ li7;
        bfv[fn] = *(const bf16x8*)&Bsm[buf][row*64 + blk*8];
      }
      __builtin_amdgcn_s_setprio(1);
      #pragma unroll
      for(int fm=0; fm<4; fm++)
        #pragma unroll
        for(int fn=0; fn<4; fn++)
          acc[fm][fn] = mfma16(af[fm], bfv[fn], acc[fm][fn]);
      __builtin_amdgcn_s_setprio(0);
    }
    __syncthreads();
    buf ^= 1;
  }
  if(OUTF32 == 0 && blockIdx.z == 2){
    // V: write transposed per head in F16.  4 consecutive s-rows pack to one 8B store.
    #pragma unroll
    for(int fm=0; fm<4; fm++){
      #pragma unroll
      for(int fn=0; fn<4; fn++){
        int col  = n0 + wcol*64 + fn*16 + li;        // h*64 + d
        int rowb = m0 + wrow*64 + fm*16 + lg*4;      // b*2048 + s
        int bq = rowb >> 11, s = rowb & 2047;
        union { f16x2 h2[2]; unsigned long long u; } o;
        o.h2[0] = pkrtz(acc[fm][fn][0], acc[fm][fn][1]);
        o.h2[1] = pkrtz(acc[fm][fn][2], acc[fm][fn][3]);
        *(unsigned long long*)&C[((size_t)(bq*16 + (col>>6))*64 + (col&63))*2048 + s] = o.u;
      }
    }
  } else {
    #pragma unroll
    for(int fm=0; fm<4; fm++){
      #pragma unroll
      for(int fn=0; fn<4; fn++){
        int col  = n0 + wcol*64 + fn*16 + li;
        int rowb = m0 + wrow*64 + fm*16 + lg*4;
        #pragma unroll
        for(int r=0;r<4;r++){
          if(OUTF32) Cf[(size_t)(rowb + r)*1024 + col] = acc[fm][fn][r];
          else       C [(size_t)(rowb + r)*1024 + col] = f2bf(acc[fm][fn][r]);
        }
      }
    }
  }
}

// ---------- kernel: flash attention v7 (round-8 proven version) ----------
// 16x16 swapped-QK, fixed-exponent softmax, 2 q-tiles per wave (32 q-rows),
// PV via mfma_f32_16x16x16_f16 with P fully lane-local (zero exchange).
// grid 512 (swizzled -> 16 qtiles x 32 bh), 4 waves, QBLK=128, KVB=64, DK=64.
__global__ __launch_bounds__(256,2) void attn_kernel(
    const unsigned short* __restrict__ Q, const unsigned short* __restrict__ K,
    const unsigned short* __restrict__ Vt, unsigned short* __restrict__ O,
    const unsigned int* __restrict__ mp)
{
  __shared__ unsigned short Ksm[2][64*64];
  __shared__ unsigned short Vsm[2][64*64];     // f16 contents
  const int wid = threadIdx.x >> 6, lane = threadIdx.x & 63;
  const int orig = blockIdx.x;
  const int wg = (orig & 7) * 64 + (orig >> 3);    // XCD swizzle (512 % 8 == 0)
  const int qt = wg & 15, bh = wg >> 4;
  const int b = bh >> 4, h = bh & 15;
  const int q0 = qt * 128;
  const int li = lane & 15, lg = lane >> 4;
  const int li7 = li & 7;

  const int rowA = b*2048 + q0 + wid*32 + li;      // lane's q-row, group A
  const int rowB = rowA + 16;                      // group B

  // Q fragments for both q-groups (Wq carries 0.125*log2e -> log2 domain)
  bf16x8 qfA[2], qfB[2];
  {
    const unsigned short* qa = Q + (size_t)rowA*1024 + h*64 + lg*8;
    const unsigned short* qb = Q + (size_t)rowB*1024 + h*64 + lg*8;
    qfA[0] = *(const bf16x8*)qa; qfA[1] = *(const bf16x8*)(qa + 32);
    qfB[0] = *(const bf16x8*)qb; qfB[1] = *(const bf16x8*)(qb + 32);
  }

  f32x4 oaccA[4] = {}, oaccB[4] = {};
  float lrowA = 0.f, lrowB = 0.f;

  const int srow = lane >> 3;
  const int sblk = (lane & 7) ^ srow;    // source-side swizzle for K/V staging

  // stage tile 0
  #pragma unroll
  for(int i=0;i<2;i++){
    int r = wid*16 + i*8 + srow;
    glds16(K  + (size_t)(b*2048 + r)*1024 + h*64 + sblk*8, &Ksm[0][(wid*16 + i*8)*64]);
    glds16(Vt + (size_t)(bh*64 + r)*2048 + sblk*8,         &Vsm[0][(wid*16 + i*8)*64]);
  }
  uint2 mwA = *(const uint2*)&mp[(size_t)rowA*64];
  uint2 mwB = *(const uint2*)&mp[(size_t)rowB*64];
  uint2 mwAn, mwBn;
  __syncthreads();

  int buf = 0;
  for(int t = 0; t < 32; ++t){
    const int kv0 = t * 64;
    if(t < 31){
      #pragma unroll
      for(int i=0;i<2;i++){
        int r = wid*16 + i*8 + srow;
        glds16(K  + (size_t)(b*2048 + kv0 + 64 + r)*1024 + h*64 + sblk*8, &Ksm[buf^1][(wid*16 + i*8)*64]);
        glds16(Vt + (size_t)(bh*64 + r)*2048 + kv0 + 64 + sblk*8,         &Vsm[buf^1][(wid*16 + i*8)*64]);
      }
      mwAn = *(const uint2*)&mp[(size_t)rowA*64 + (size_t)((kv0 + 64) >> 5)];
      mwBn = *(const uint2*)&mp[(size_t)rowB*64 + (size_t)((kv0 + 64) >> 5)];
    }
    // S^T tiles for both q-groups: pX[f][j] = S[q][k=f*16+lg*4+j] (log2 domain)
    f32x4 pA[4], pB[4];
    __builtin_amdgcn_s_setprio(1);
    #pragma unroll
    for(int f=0; f<4; f++){
      f32x4 sa = {0.f,0.f,0.f,0.f}, sb = {0.f,0.f,0.f,0.f};
      #pragma unroll
      for(int kf=0; kf<2; kf++){
        int blk = (kf*4 + lg) ^ li7;
        bf16x8 kfr = *(const bf16x8*)&Ksm[buf][(f*16 + li)*64 + blk*8];
        sa = mfma16(kfr, qfA[kf], sa);
        sb = mfma16(kfr, qfB[kf], sb);
      }
      pA[f] = sa; pB[f] = sb;
    }
    __builtin_amdgcn_s_setprio(0);
    // fused softmax + PV, per k-16 subtile f: P stays lane-local (A-frag of 16x16x16)
    #pragma unroll
    for(int f=0; f<4; f++){
      unsigned int wA = (f < 2) ? mwA.x : mwA.y;
      unsigned int wB = (f < 2) ? mwB.x : mwB.y;
      float eA[4], eB[4];
      #pragma unroll
      for(int j=0;j<4;j++){
        unsigned int bitA = (wA >> ((f & 1)*16 + lg*4 + j)) & 1u;
        unsigned int bitB = (wB >> ((f & 1)*16 + lg*4 + j)) & 1u;
        float vA = exp2v(pA[f][j]);
        float vB = exp2v(pB[f][j]);
        eA[j] = bitA ? 0.f : vA;
        eB[j] = bitB ? 0.f : vB;
      }
      lrowA += (eA[0] + eA[1]) + (eA[2] + eA[3]);
      lrowB += (eB[0] + eB[1]) + (eB[2] + eB[3]);
      union { f16x2 h2[2]; f16x4 v; } ua, ub;
      ua.h2[0] = pkrtz(eA[0], eA[1]);
      ua.h2[1] = pkrtz(eA[2], eA[3]);
      ub.h2[0] = pkrtz(eB[0], eB[1]);
      ub.h2[1] = pkrtz(eB[2], eB[3]);
      const int blk = (f*2 + (lg >> 1)) ^ li7;
      const int sub = (lg & 1)*4;
      __builtin_amdgcn_s_setprio(1);
      #pragma unroll
      for(int dt=0; dt<4; dt++){
        f16x4 vf = *(const f16x4*)&Vsm[buf][(dt*16 + li)*64 + blk*8 + sub];
        oaccA[dt] = mfma16h(ua.v, vf, oaccA[dt]);
        oaccB[dt] = mfma16h(ub.v, vf, oaccB[dt]);
      }
      __builtin_amdgcn_s_setprio(0);
    }
    __syncthreads();
    mwA = mwAn; mwB = mwBn;
    buf ^= 1;
  }
  // reduce lane-partial sums (lanes sharing li), normalize, store both groups
  float rsA = lrowA, rsB = lrowB;
  rsA += __shfl_xor(rsA, 16); rsA += __shfl_xor(rsA, 32);
  rsB += __shfl_xor(rsB, 16); rsB += __shfl_xor(rsB, 32);
  float invA = 1.0f / rsA;               // valid for q-row (group A, index li)
  float invB = 1.0f / rsB;
  #pragma unroll
  for(int r=0;r<4;r++){
    float ioA = __shfl(invA, lg*4 + r);
    float ioB = __shfl(invB, lg*4 + r);
    size_t rbA = (size_t)(b*2048 + q0 + wid*32 + lg*4 + r);
    size_t rbB = rbA + 16;
    #pragma unroll
    for(int dt=0; dt<4; dt++){
      O[rbA*1024 + h*64 + 16*dt + li] = f2bf(oaccA[dt][r] * ioA);
      O[rbB*1024 + h*64 + 16*dt + li] = f2bf(oaccB[dt][r] * ioB);
    }
  }
}

// ---------- launch ----------
extern "C" void kernel_launch(void* const* d_in, const int* in_sizes, int n_in,
                              void* d_out, int out_size, void* d_ws, size_t ws_size,
                              hipStream_t stream)
{
  const float* q_in = (const float*)d_in[0];
  const float* k_in = (const float*)d_in[1];
  const float* v_in = (const float*)d_in[2];
  const unsigned char* mask = (const unsigned char*)d_in[3];
  const float* Wq = (const float*)d_in[4];
  const float* Wk = (const float*)d_in[5];
  const float* Wv = (const float*)d_in[6];
  const float* Wo = (const float*)d_in[7];

  char* ws = (char*)d_ws;
  const size_t MB = 1024*1024;
  unsigned short* XQ = (unsigned short*)(ws + 256);           // 8 MB
  unsigned short* XK = (unsigned short*)(ws + 256 + 8*MB);    // 8 MB
  unsigned short* XV = (unsigned short*)(ws + 256 + 16*MB);   // 8 MB
  unsigned short* WT = (unsigned short*)(ws + 256 + 24*MB);   // 8 MB (4 matrices)
  unsigned short* Qb = (unsigned short*)(ws + 256 + 32*MB);   // 8 MB
  unsigned short* Kb = (unsigned short*)(ws + 256 + 40*MB);   // 8 MB
  unsigned short* Vt = (unsigned short*)(ws + 256 + 48*MB);   // 8 MB (f16, transposed, from GEMM)
  unsigned short* Ob = XQ;                                    // attention output (bf16)
  unsigned int*   mpk= (unsigned int*)XV;                     // packed mask (1 MB, after GEMM reads XV)

  cvt3_kernel<<<dim3(2048,3), 256, 0, stream>>>(q_in, k_in, v_in, XQ);
  transW_kernel<<<dim3(256,4), 256, 0, stream>>>(Wq, Wk, Wv, Wo, WT);
  gemm_bt<0><<<dim3(32,8,3), 256, 0, stream>>>(XQ, XK, XV,
                                               WT, WT + 1048576, WT + 2097152,
                                               Qb, Kb, Vt, nullptr);
  pack_mask_kernel<<<1024, 256, 0, stream>>>(mask, mpk);
  attn_kernel<<<512, 256, 0, stream>>>(Qb, Kb, Vt, Ob, mpk);
  gemm_bt<1><<<dim3(32,8,1), 256, 0, stream>>>(Ob, Ob, Ob,
                                               WT + 3*1048576, WT + 3*1048576, WT + 3*1048576,
                                               nullptr, nullptr, nullptr, (float*)d_out);
}

// Round 11
// 145.466 us; speedup vs baseline: 2.0989x; 1.0387x over previous
//
#include <hip/hip_runtime.h>
#include <hip/hip_bf16.h>

// ---------- types ----------
typedef float f32x4 __attribute__((ext_vector_type(4)));
typedef __bf16 bf16x8 __attribute__((ext_vector_type(8)));
typedef _Float16 f16x2 __attribute__((ext_vector_type(2)));
typedef _Float16 f16x4 __attribute__((ext_vector_type(4)));

// fp32 -> bf16 RNE
__device__ __forceinline__ unsigned short f2bf(float f){
  unsigned int u = __builtin_bit_cast(unsigned int, f);
  u += 0x7fffu + ((u >> 16) & 1u);
  return (unsigned short)(u >> 16);
}
__device__ __forceinline__ float bf2f(unsigned short h){
  return __builtin_bit_cast(float, (unsigned int)h << 16);
}

// packed f32x2 -> f16x2 (v_cvt_pkrtz_f16_f32), with type-identity fix
__device__ __forceinline__ f16x2 pkrtz(float a, float b){
  return __builtin_bit_cast(f16x2, __builtin_amdgcn_cvt_pkrtz(a, b));
}

__device__ __forceinline__ void glds16(const void* g, void* l){
  __builtin_amdgcn_global_load_lds((const __attribute__((address_space(1))) void*)g,
                                   (__attribute__((address_space(3))) void*)l, 16, 0, 0);
}

__device__ __forceinline__ f32x4 mfma16(bf16x8 a, bf16x8 b, f32x4 c){
  return __builtin_amdgcn_mfma_f32_16x16x32_bf16(a, b, c, 0, 0, 0);
}
__device__ __forceinline__ f32x4 mfma16h(f16x4 a, f16x4 b, f32x4 c){
  return __builtin_amdgcn_mfma_f32_16x16x16f16(a, b, c, 0, 0, 0);
}

#if __has_builtin(__builtin_amdgcn_exp2f)
__device__ __forceinline__ float exp2v(float x){ return __builtin_amdgcn_exp2f(x); }
#else
__device__ __forceinline__ float exp2v(float x){ return exp2f(x); }
#endif

// ---------- kernel: pack mask into bits, self-detecting dtype ----------
__global__ void pack_mask_kernel(const unsigned char* __restrict__ m8,
                                 unsigned int* __restrict__ mp){
  const int wid = threadIdx.x >> 6, lane = threadIdx.x & 63;
  const int row = blockIdx.x * 4 + wid;            // 0..4095 (b*2048+q)
  const unsigned int* w32 = (const unsigned int*)m8;
  int bad = 0;
  #pragma unroll
  for(int c = 0; c < 1024; c += 64) bad |= (w32[c + lane] > 1u);
  const int is32 = !__any(bad);
  const int* m32 = (const int*)m8;
  for(int c0 = 0; c0 < 2048; c0 += 64){
    int mv = is32 ? m32[(size_t)row*2048 + c0 + lane]
                  : (int)m8[(size_t)row*2048 + c0 + lane];
    unsigned long long b = __ballot(mv != 0);
    if(lane == 0){
      mp[(size_t)row*64 + (c0 >> 5)]     = (unsigned int)b;
      mp[(size_t)row*64 + (c0 >> 5) + 1] = (unsigned int)(b >> 32);
    }
  }
}

// ---------- kernel: fp32 -> bf16 convert, all three of q/k/v ----------
__global__ void cvt3_kernel(const float* __restrict__ qs, const float* __restrict__ ks,
                            const float* __restrict__ vs, unsigned short* __restrict__ dst){
  const float* src = (blockIdx.y==0)?qs:(blockIdx.y==1)?ks:vs;
  unsigned short* d = dst + (size_t)blockIdx.y * 4194304;
  int i = blockIdx.x * 256 + threadIdx.x;
  const float4* s = (const float4*)src;
  float4 a = s[2*i], b = s[2*i+1];
  union { unsigned short h[8]; uint4 v; } o;
  o.h[0]=f2bf(a.x); o.h[1]=f2bf(a.y); o.h[2]=f2bf(a.z); o.h[3]=f2bf(a.w);
  o.h[4]=f2bf(b.x); o.h[5]=f2bf(b.y); o.h[6]=f2bf(b.z); o.h[7]=f2bf(b.w);
  ((uint4*)d)[i] = o.v;
}

// ---------- kernel: W[1024][1024] f32 -> W^T bf16 (Wq scaled by 0.125*log2e) ----------
__global__ void transW_kernel(const float* __restrict__ Wq, const float* __restrict__ Wk,
                              const float* __restrict__ Wv, const float* __restrict__ Wo,
                              unsigned short* __restrict__ WT){
  const float* W = (blockIdx.y==0)?Wq:(blockIdx.y==1)?Wk:(blockIdx.y==2)?Wv:Wo;
  const float scale = (blockIdx.y==0) ? 0.1803368801111601f : 1.0f;
  unsigned short* D = WT + (size_t)blockIdx.y * 1048576;
  int r0 = (blockIdx.x >> 4) * 64, c0 = (blockIdx.x & 15) * 64;
  __shared__ unsigned short T[64][65];
  int t = threadIdx.x;
  {
    int r = t >> 2, cb = (t & 3) * 16;
    const float4* src = (const float4*)(W + (size_t)(r0 + r) * 1024 + (c0 + cb));
    float4 v0 = src[0], v1 = src[1], v2 = src[2], v3 = src[3];
    float vals[16] = {v0.x,v0.y,v0.z,v0.w, v1.x,v1.y,v1.z,v1.w,
                      v2.x,v2.y,v2.z,v2.w, v3.x,v3.y,v3.z,v3.w};
    #pragma unroll
    for(int j=0;j<16;j++) T[cb + j][r] = f2bf(vals[j] * scale);
  }
  __syncthreads();
  {
    int c = t >> 2, rb = (t & 3) * 16;
    union { unsigned short h[16]; uint4 v[2]; } o;
    #pragma unroll
    for(int j=0;j<16;j++) o.h[j] = T[c][rb + j];
    uint4* dp = (uint4*)(D + (size_t)(c0 + c) * 1024 + (r0 + rb));
    dp[0] = o.v[0]; dp[1] = o.v[1];
  }
}

// ---------- kernel: C[M=4096][N=1024] = A @ BT^T, bf16, 128x128 tile, BK=64 ----------
// (round-8 proven single-buffer version)
template<int OUTF32>
__global__ __launch_bounds__(256,2) void gemm_bt(
    const unsigned short* __restrict__ A0, const unsigned short* __restrict__ A1, const unsigned short* __restrict__ A2,
    const unsigned short* __restrict__ B0, const unsigned short* __restrict__ B1, const unsigned short* __restrict__ B2,
    unsigned short* __restrict__ C0, unsigned short* __restrict__ C1, unsigned short* __restrict__ C2,
    float* __restrict__ Cf)
{
  const unsigned short* A  = (blockIdx.z==0)?A0:(blockIdx.z==1)?A1:A2;
  const unsigned short* BT = (blockIdx.z==0)?B0:(blockIdx.z==1)?B1:B2;
  unsigned short* C        = (blockIdx.z==0)?C0:(blockIdx.z==1)?C1:C2;
  __shared__ unsigned short Asm[128*64];
  __shared__ unsigned short Bsm[128*64];
  const int wid = threadIdx.x >> 6, lane = threadIdx.x & 63;
  const int m0 = blockIdx.x * 128, n0 = blockIdx.y * 128;
  const int wrow = wid >> 1, wcol = wid & 1;
  const int li = lane & 15, lg = lane >> 4, li7 = lane & 7;
  f32x4 acc[4][4] = {};
  const int sr = lane >> 3;       // 0..7 (row within 8-row chunk)
  const int sc = lane & 7;        // 0..7 (16B block within 128B row)

  for(int kt = 0; kt < 16; ++kt){
    const int kofs = kt * 64;
    #pragma unroll
    for(int i=0;i<4;i++){
      int r = wid*32 + i*8 + sr;
      int blk = sc ^ sr;
      glds16(A  + (size_t)(m0 + r)*1024 + kofs + blk*8, &Asm[(wid*32 + i*8)*64]);
      glds16(BT + (size_t)(n0 + r)*1024 + kofs + blk*8, &Bsm[(wid*32 + i*8)*64]);
    }
    __syncthreads();
    #pragma unroll
    for(int kk=0; kk<2; kk++){
      bf16x8 af[4], bfv[4];
      #pragma unroll
      for(int fm=0; fm<4; fm++){
        int row = wrow*64 + fm*16 + li;
        int blk = (kk*4 + lg) ^ li7;
        af[fm] = *(const bf16x8*)&Asm[row*64 + blk*8];
      }
      #pragma unroll
      for(int fn=0; fn<4; fn++){
        int row = wcol*64 + fn*16 + li;
        int blk = (kk*4 + lg) ^ li7;
        bfv[fn] = *(const bf16x8*)&Bsm[row*64 + blk*8];
      }
      __builtin_amdgcn_s_setprio(1);
      #pragma unroll
      for(int fm=0; fm<4; fm++)
        #pragma unroll
        for(int fn=0; fn<4; fn++)
          acc[fm][fn] = mfma16(af[fm], bfv[fn], acc[fm][fn]);
      __builtin_amdgcn_s_setprio(0);
    }
    __syncthreads();
  }
  if(OUTF32 == 0 && blockIdx.z == 2){
    #pragma unroll
    for(int fm=0; fm<4; fm++){
      #pragma unroll
      for(int fn=0; fn<4; fn++){
        int col  = n0 + wcol*64 + fn*16 + li;        // h*64 + d
        int rowb = m0 + wrow*64 + fm*16 + lg*4;      // b*2048 + s
        int bq = rowb >> 11, s = rowb & 2047;
        union { f16x2 h2[2]; unsigned long long u; } o;
        o.h2[0] = pkrtz(acc[fm][fn][0], acc[fm][fn][1]);
        o.h2[1] = pkrtz(acc[fm][fn][2], acc[fm][fn][3]);
        *(unsigned long long*)&C[((size_t)(bq*16 + (col>>6))*64 + (col&63))*2048 + s] = o.u;
      }
    }
  } else {
    #pragma unroll
    for(int fm=0; fm<4; fm++){
      #pragma unroll
      for(int fn=0; fn<4; fn++){
        int col  = n0 + wcol*64 + fn*16 + li;
        int rowb = m0 + wrow*64 + fm*16 + lg*4;
        #pragma unroll
        for(int r=0;r<4;r++){
          if(OUTF32) Cf[(size_t)(rowb + r)*1024 + col] = acc[fm][fn][r];
          else       C [(size_t)(rowb + r)*1024 + col] = f2bf(acc[fm][fn][r]);
        }
      }
    }
  }
}

// ---------- kernel: flash attention v9 (v7 + KVB=128, one barrier per 128-KV tile) ----------
// 16x16 swapped-QK, fixed-exponent softmax, 2 q-groups/wave, lane-local f16 PV.
// grid 512 (swizzled -> 16 qtiles x 32 bh), 4 waves, QBLK=128, KVB=128 (2x64 halves).
__global__ __launch_bounds__(256,2) void attn_kernel(
    const unsigned short* __restrict__ Q, const unsigned short* __restrict__ K,
    const unsigned short* __restrict__ Vt, unsigned short* __restrict__ O,
    const unsigned int* __restrict__ mp)
{
  __shared__ unsigned short Ksm[2][128*64];    // 128 kv-rows x 64 dk
  __shared__ unsigned short Vsm[2][64*128];    // 64 d-rows x 128 s (f16)
  const int wid = threadIdx.x >> 6, lane = threadIdx.x & 63;
  const int orig = blockIdx.x;
  const int wg = (orig & 7) * 64 + (orig >> 3);    // XCD swizzle (512 % 8 == 0)
  const int qt = wg & 15, bh = wg >> 4;
  const int b = bh >> 4, h = bh & 15;
  const int q0 = qt * 128;
  const int li = lane & 15, lg = lane >> 4;
  const int li7 = li & 7;

  const int rowA = b*2048 + q0 + wid*32 + li;      // lane's q-row, group A
  const int rowB = rowA + 16;                      // group B

  // Q fragments (Wq carries 0.125*log2e -> log2 domain)
  bf16x8 qfA[2], qfB[2];
  {
    const unsigned short* qa = Q + (size_t)rowA*1024 + h*64 + lg*8;
    const unsigned short* qb = Q + (size_t)rowB*1024 + h*64 + lg*8;
    qfA[0] = *(const bf16x8*)qa; qfA[1] = *(const bf16x8*)(qa + 32);
    qfB[0] = *(const bf16x8*)qb; qfB[1] = *(const bf16x8*)(qb + 32);
  }

  f32x4 oaccA[4] = {}, oaccB[4] = {};
  float lrowA = 0.f, lrowB = 0.f;

  // K staging: 8 rows of 128B per glds; source-side 8-block swizzle
  const int kr  = lane >> 3;                 // 0..7
  const int kblk = (lane & 7) ^ kr;
  // V staging: 4 rows of 256B per glds; source-side 16-block swizzle
  const int vr  = lane >> 4;                 // 0..3
  const int vc  = lane & 15;

  // stage tile 0
  #pragma unroll
  for(int i=0;i<4;i++){
    int krow = wid*32 + i*8 + kr;
    glds16(K + (size_t)(b*2048 + krow)*1024 + h*64 + kblk*8, &Ksm[0][(wid*32 + i*8)*64]);
  }
  #pragma unroll
  for(int i=0;i<4;i++){
    int vrow = wid*16 + i*4 + vr;
    int vb = vc ^ (vrow & 15);
    glds16(Vt + (size_t)(bh*64 + vrow)*2048 + vb*8, &Vsm[0][(wid*16 + i*4)*128]);
  }
  uint4 mwA = *(const uint4*)&mp[(size_t)rowA*64];
  uint4 mwB = *(const uint4*)&mp[(size_t)rowB*64];
  uint4 mwAn, mwBn;
  __syncthreads();

  int buf = 0;
  for(int t = 0; t < 16; ++t){
    if(t < 15){
      const int kv = (t + 1) * 128;
      #pragma unroll
      for(int i=0;i<4;i++){
        int krow = wid*32 + i*8 + kr;
        glds16(K + (size_t)(b*2048 + kv + krow)*1024 + h*64 + kblk*8, &Ksm[buf^1][(wid*32 + i*8)*64]);
      }
      #pragma unroll
      for(int i=0;i<4;i++){
        int vrow = wid*16 + i*4 + vr;
        int vb = vc ^ (vrow & 15);
        glds16(Vt + (size_t)(bh*64 + vrow)*2048 + kv + vb*8, &Vsm[buf^1][(wid*16 + i*4)*128]);
      }
      mwAn = *(const uint4*)&mp[(size_t)rowA*64 + (size_t)(t + 1)*4];
      mwBn = *(const uint4*)&mp[(size_t)rowB*64 + (size_t)(t + 1)*4];
    }
    #pragma unroll
    for(int hlf = 0; hlf < 2; ++hlf){
      // S^T tiles: pX[f][j] = S[q][k = hlf*64 + f*16 + lg*4 + j] (log2 domain)
      f32x4 pA[4], pB[4];
      __builtin_amdgcn_s_setprio(1);
      #pragma unroll
      for(int f=0; f<4; f++){
        f32x4 sa = {0.f,0.f,0.f,0.f}, sb = {0.f,0.f,0.f,0.f};
        #pragma unroll
        for(int kf=0; kf<2; kf++){
          int blk = (kf*4 + lg) ^ li7;
          bf16x8 kfr = *(const bf16x8*)&Ksm[buf][(hlf*64 + f*16 + li)*64 + blk*8];
          sa = mfma16(kfr, qfA[kf], sa);
          sb = mfma16(kfr, qfB[kf], sb);
        }
        pA[f] = sa; pB[f] = sb;
      }
      __builtin_amdgcn_s_setprio(0);
      const unsigned int wA0 = hlf ? mwA.z : mwA.x, wA1 = hlf ? mwA.w : mwA.y;
      const unsigned int wB0 = hlf ? mwB.z : mwB.x, wB1 = hlf ? mwB.w : mwB.y;
      // fused softmax + PV per k-16 subtile f
      #pragma unroll
      for(int f=0; f<4; f++){
        unsigned int wA = (f < 2) ? wA0 : wA1;
        unsigned int wB = (f < 2) ? wB0 : wB1;
        float eA[4], eB[4];
        #pragma unroll
        for(int j=0;j<4;j++){
          unsigned int bitA = (wA >> ((f & 1)*16 + lg*4 + j)) & 1u;
          unsigned int bitB = (wB >> ((f & 1)*16 + lg*4 + j)) & 1u;
          float vA = exp2v(pA[f][j]);
          float vB = exp2v(pB[f][j]);
          eA[j] = bitA ? 0.f : vA;
          eB[j] = bitB ? 0.f : vB;
        }
        lrowA += (eA[0] + eA[1]) + (eA[2] + eA[3]);
        lrowB += (eB[0] + eB[1]) + (eB[2] + eB[3]);
        union { f16x2 h2[2]; f16x4 v; } ua, ub;
        ua.h2[0] = pkrtz(eA[0], eA[1]);
        ua.h2[1] = pkrtz(eA[2], eA[3]);
        ub.h2[0] = pkrtz(eB[0], eB[1]);
        ub.h2[1] = pkrtz(eB[2], eB[3]);
        // V B-frag: row = dt*16+li (d), col block = hlf*8 + f*2 + (lg>>1), 16-blk swizzle by li
        const int cb = (hlf*8 + f*2 + (lg >> 1)) ^ li;
        const int sub = (lg & 1)*4;
        __builtin_amdgcn_s_setprio(1);
        #pragma unroll
        for(int dt=0; dt<4; dt++){
          f16x4 vf = *(const f16x4*)&Vsm[buf][(dt*16 + li)*128 + cb*8 + sub];
          oaccA[dt] = mfma16h(ua.v, vf, oaccA[dt]);
          oaccB[dt] = mfma16h(ub.v, vf, oaccB[dt]);
        }
        __builtin_amdgcn_s_setprio(0);
      }
    }
    __syncthreads();
    mwA = mwAn; mwB = mwBn;
    buf ^= 1;
  }
  // reduce lane-partial sums (lanes sharing li), normalize, store both groups
  float rsA = lrowA, rsB = lrowB;
  rsA += __shfl_xor(rsA, 16); rsA += __shfl_xor(rsA, 32);
  rsB += __shfl_xor(rsB, 16); rsB += __shfl_xor(rsB, 32);
  float invA = 1.0f / rsA;
  float invB = 1.0f / rsB;
  #pragma unroll
  for(int r=0;r<4;r++){
    float ioA = __shfl(invA, lg*4 + r);
    float ioB = __shfl(invB, lg*4 + r);
    size_t rbA = (size_t)(b*2048 + q0 + wid*32 + lg*4 + r);
    size_t rbB = rbA + 16;
    #pragma unroll
    for(int dt=0; dt<4; dt++){
      O[rbA*1024 + h*64 + 16*dt + li] = f2bf(oaccA[dt][r] * ioA);
      O[rbB*1024 + h*64 + 16*dt + li] = f2bf(oaccB[dt][r] * ioB);
    }
  }
}

// ---------- launch ----------
extern "C" void kernel_launch(void* const* d_in, const int* in_sizes, int n_in,
                              void* d_out, int out_size, void* d_ws, size_t ws_size,
                              hipStream_t stream)
{
  const float* q_in = (const float*)d_in[0];
  const float* k_in = (const float*)d_in[1];
  const float* v_in = (const float*)d_in[2];
  const unsigned char* mask = (const unsigned char*)d_in[3];
  const float* Wq = (const float*)d_in[4];
  const float* Wk = (const float*)d_in[5];
  const float* Wv = (const float*)d_in[6];
  const float* Wo = (const float*)d_in[7];

  char* ws = (char*)d_ws;
  const size_t MB = 1024*1024;
  unsigned short* XQ = (unsigned short*)(ws + 256);           // 8 MB
  unsigned short* XK = (unsigned short*)(ws + 256 + 8*MB);    // 8 MB
  unsigned short* XV = (unsigned short*)(ws + 256 + 16*MB);   // 8 MB
  unsigned short* WT = (unsigned short*)(ws + 256 + 24*MB);   // 8 MB (4 matrices)
  unsigned short* Qb = (unsigned short*)(ws + 256 + 32*MB);   // 8 MB
  unsigned short* Kb = (unsigned short*)(ws + 256 + 40*MB);   // 8 MB
  unsigned short* Vt = (unsigned short*)(ws + 256 + 48*MB);   // 8 MB (f16, transposed, from GEMM)
  unsigned short* Ob = XQ;                                    // attention output (bf16)
  unsigned int*   mpk= (unsigned int*)XV;                     // packed mask (1 MB, after GEMM reads XV)

  cvt3_kernel<<<dim3(2048,3), 256, 0, stream>>>(q_in, k_in, v_in, XQ);
  transW_kernel<<<dim3(256,4), 256, 0, stream>>>(Wq, Wk, Wv, Wo, WT);
  gemm_bt<0><<<dim3(32,8,3), 256, 0, stream>>>(XQ, XK, XV,
                                               WT, WT + 1048576, WT + 2097152,
                                               Qb, Kb, Vt, nullptr);
  pack_mask_kernel<<<1024, 256, 0, stream>>>(mask, mpk);
  attn_kernel<<<512, 256, 0, stream>>>(Qb, Kb, Vt, Ob, mpk);
  gemm_bt<1><<<dim3(32,8,1), 256, 0, stream>>>(Ob, Ob, Ob,
                                               WT + 3*1048576, WT + 3*1048576, WT + 3*1048576,
                                               nullptr, nullptr, nullptr, (float*)d_out);
}